// Round 1
// baseline (47.307 us; speedup 1.0000x reference)
//
#include <hip/hip_runtime.h>

// LIF leaky integrator: v_t = v_{t-1} + (x_t - v_{t-1}) * 0.5, v0 = 0.
// x: [T=1024, B=16, N=2048] f32, out: v_seq same shape.
// Strategy: chunk T into C chunks of L; each thread owns one float4 group
// for one chunk. Initial state recovered by scanning the last WARM=32 steps
// of the previous chunk (decay 0.5^32 makes older history < fp32 ulp).

constexpr int T   = 1024;
constexpr int E4  = 8192;   // (B*N)/4 float4 groups per timestep
constexpr int L   = 128;    // chunk length
constexpr int C   = T / L;  // 8 chunks
constexpr int WARM = 32;    // warm-up steps (0.5^32 ~ 2.3e-10)

__global__ __launch_bounds__(256) void lif_chunked(const float4* __restrict__ x,
                                                   float4* __restrict__ out) {
    const int gid = blockIdx.x * 256 + threadIdx.x;
    const int g = gid & (E4 - 1);   // float4 group index (fast dim -> coalesced)
    const int c = gid >> 13;        // chunk index

    const int t0 = c * L;
    float4 v = make_float4(0.f, 0.f, 0.f, 0.f);

    if (c > 0) {
        const float4* p = x + (size_t)(t0 - WARM) * E4 + g;
        #pragma unroll 4
        for (int k = 0; k < WARM; ++k) {
            float4 xv = p[(size_t)k * E4];
            v.x = fmaf(0.5f, xv.x - v.x, v.x);
            v.y = fmaf(0.5f, xv.y - v.y, v.y);
            v.z = fmaf(0.5f, xv.z - v.z, v.z);
            v.w = fmaf(0.5f, xv.w - v.w, v.w);
        }
    }

    const float4* p = x   + (size_t)t0 * E4 + g;
    float4*       q = out + (size_t)t0 * E4 + g;
    #pragma unroll 4
    for (int k = 0; k < L; ++k) {
        float4 xv = p[(size_t)k * E4];
        v.x = fmaf(0.5f, xv.x - v.x, v.x);
        v.y = fmaf(0.5f, xv.y - v.y, v.y);
        v.z = fmaf(0.5f, xv.z - v.z, v.z);
        v.w = fmaf(0.5f, xv.w - v.w, v.w);
        q[(size_t)k * E4] = v;
    }
}

extern "C" void kernel_launch(void* const* d_in, const int* in_sizes, int n_in,
                              void* d_out, int out_size, void* d_ws, size_t ws_size,
                              hipStream_t stream) {
    const float4* x = (const float4*)d_in[0];
    float4* out = (float4*)d_out;
    const int total_threads = E4 * C;        // 65536
    const int blocks = total_threads / 256;  // 256
    lif_chunked<<<blocks, 256, 0, stream>>>(x, out);
}